// Round 9
// baseline (518.789 us; speedup 1.0000x reference)
//
#include <hip/hip_runtime.h>

#define THREADS 256
#define NPTS 8192
#define BATCH 4
#define NSETS 8                 // dir*4 + batch
#define NBINS 128
#define NMINS (2 * BATCH * NPTS)            // 65536 (fallback path)

typedef float f4 __attribute__((ext_vector_type(4)));

// ---------------- ws layout (binned path) ----------------
// [0)            : float4 sortedT[8][8192]      = 1,048,576 B  (-2x,-2y,-2z,|t|^2)
// [1048576)      : uint   binStart[8][NBINS+1]  = 4,128 B
// [1052704)      : float  meta[8][2]            = 64 B  (xmin, inv)
#define OFF_BINSTART 1048576
#define OFF_META     1052704
#define WS_NEEDED    (OFF_META + 64)

// ================= prep: per-set counting sort by x =================
__global__ __launch_bounds__(1024) void chamfer_prep(
    const float* __restrict__ p1, const float* __restrict__ p2,
    f4* __restrict__ sortedT, unsigned int* __restrict__ binStart,
    float* __restrict__ meta, float* __restrict__ out)
{
    const int set = blockIdx.x;          // 0..7
    const int dir = set >> 2;
    const int b   = set & 3;
    const float* tsrc = dir ? p1 : p2;   // dir0 targets = p2, dir1 targets = p1
    const float* tp = tsrc + (size_t)b * NPTS * 3;
    const int tid = threadIdx.x;

    float x[8], y[8], z[8];
    int   bin[8];
    float lmin = 3.0e38f, lmax = -3.0e38f;
#pragma unroll
    for (int k = 0; k < 8; ++k) {
        const int i = tid + k * 1024;
        x[k] = tp[i * 3 + 0];
        y[k] = tp[i * 3 + 1];
        z[k] = tp[i * 3 + 2];
        lmin = fminf(lmin, x[k]);
        lmax = fmaxf(lmax, x[k]);
    }
    // wave then block min/max
#pragma unroll
    for (int off = 1; off < 64; off <<= 1) {
        lmin = fminf(lmin, __shfl_xor(lmin, off, 64));
        lmax = fmaxf(lmax, __shfl_xor(lmax, off, 64));
    }
    __shared__ float smin[16], smax[16];
    __shared__ float sxminv[2];
    if ((tid & 63) == 0) { smin[tid >> 6] = lmin; smax[tid >> 6] = lmax; }
    __syncthreads();
    if (tid == 0) {
        float m = 3.0e38f, M = -3.0e38f;
        for (int w = 0; w < 16; ++w) { m = fminf(m, smin[w]); M = fmaxf(M, smax[w]); }
        float inv = (M > m) ? (float)NBINS / (M - m) : 0.0f;
        sxminv[0] = m; sxminv[1] = inv;
    }
    __syncthreads();
    const float xmin = sxminv[0], inv = sxminv[1];

    __shared__ unsigned int hist[NBINS];
    __shared__ unsigned int offs[NBINS + 1];
    for (int i = tid; i < NBINS; i += 1024) hist[i] = 0u;
    __syncthreads();
#pragma unroll
    for (int k = 0; k < 8; ++k) {
        int bi = (int)((x[k] - xmin) * inv);
        bi = bi < 0 ? 0 : (bi > NBINS - 1 ? NBINS - 1 : bi);
        bin[k] = bi;
        atomicAdd(&hist[bi], 1u);
    }
    __syncthreads();
    if (tid == 0) {
        unsigned int run = 0;
        for (int i = 0; i < NBINS; ++i) { offs[i] = run; run += hist[i]; }
        offs[NBINS] = run;               // == 8192
    }
    __syncthreads();
    for (int i = tid; i <= NBINS; i += 1024)
        binStart[set * (NBINS + 1) + i] = offs[i];
    __syncthreads();                     // binStart written before offs mutates
#pragma unroll
    for (int k = 0; k < 8; ++k) {
        unsigned int pos = atomicAdd(&offs[bin[k]], 1u);
        sortedT[(size_t)set * NPTS + pos] =
            f4{-2.0f * x[k], -2.0f * y[k], -2.0f * z[k],
               fmaf(x[k], x[k], fmaf(y[k], y[k], z[k] * z[k]))};
    }
    if (tid == 0) {
        meta[2 * set + 0] = xmin;
        meta[2 * set + 1] = inv;
        if (set == 0) out[0] = 0.0f;
    }
}

// ================= query: exact NN via ring scan over bins =================
__global__ __launch_bounds__(THREADS) void chamfer_query(
    const float* __restrict__ p1, const float* __restrict__ p2,
    const f4* __restrict__ sortedT, const unsigned int* __restrict__ binStart,
    const float* __restrict__ meta, float* __restrict__ out)
{
    const int tid = threadIdx.x;
    const int gq  = blockIdx.x * THREADS + tid;   // 0..65535
    const int set = gq >> 13;                     // dir*4+b (uniform per block)
    const int dir = set >> 2;
    const int b   = set & 3;
    const int q   = gq & (NPTS - 1);

    const float* qsrc = dir ? p2 : p1;            // queries = opposite set
    const float* pq = qsrc + ((size_t)b * NPTS + q) * 3;
    const float qx = pq[0], qy = pq[1], qz = pq[2];
    const float q2 = fmaf(qx, qx, fmaf(qy, qy, qz * qz));

    const float xmin = meta[2 * set + 0];
    const float inv  = meta[2 * set + 1];
    const float binw = (inv > 0.0f) ? 1.0f / inv : 0.0f;
    const unsigned int* bs = binStart + set * (NBINS + 1);
    const f4* __restrict__ T = sortedT + (size_t)set * NPTS;

    float fb = (qx - xmin) * inv;
    int b0 = fb < 0.0f ? 0 : (fb >= (float)NBINS ? NBINS - 1 : (int)fb);

    float best = 3.0e38f;                         // tracks dist - q2

    // scan a bin [s,e), 2-wide for load pipelining
    auto scanBin = [&](int s, int e) {
        int pos = s;
        for (; pos + 1 < e; pos += 2) {
            f4 t0 = T[pos], t1 = T[pos + 1];
            float d0 = fmaf(qz, t0.z, t0.w);
            d0 = fmaf(qy, t0.y, d0);
            d0 = fmaf(qx, t0.x, d0);
            float d1 = fmaf(qz, t1.z, t1.w);
            d1 = fmaf(qy, t1.y, d1);
            d1 = fmaf(qx, t1.x, d1);
            best = fminf(fminf(best, d0), d1);
        }
        if (pos < e) {
            f4 t0 = T[pos];
            float d0 = fmaf(qz, t0.z, t0.w);
            d0 = fmaf(qy, t0.y, d0);
            d0 = fmaf(qx, t0.x, d0);
            best = fminf(best, d0);
        }
    };

    scanBin(bs[b0], bs[b0 + 1]);

    int bl = b0 - 1, br = b0 + 1;
    for (int iter = 0; iter < NBINS; ++iter) {
        float bd = fmaxf(best + q2, 0.0f);        // true best squared distance
        bd = fmaf(bd, 2.0e-6f, bd) + 1.0e-30f;    // conservative ulp margin
        bool goL = false, goR = false;
        if (bl >= 0) {
            float e = qx - (xmin + (float)(bl + 1) * binw);  // near-edge dist
            e = fmaxf(e, 0.0f);
            goL = (e * e <= bd);
        }
        if (br < NBINS) {
            float e = (xmin + (float)br * binw) - qx;
            e = fmaxf(e, 0.0f);
            goR = (e * e <= bd);
        }
        if (goL) { scanBin(bs[bl], bs[bl + 1]); --bl; }
        if (goR) { scanBin(bs[br], bs[br + 1]); ++br; }
        if (!goL && !goR) break;
    }

    float v = fmaxf(best + q2, 0.0f);

    // block sum -> single atomicAdd
#pragma unroll
    for (int off = 1; off < 64; off <<= 1)
        v += __shfl_xor(v, off, 64);
    __shared__ float part[THREADS / 64];
    if ((tid & 63) == 0) part[tid >> 6] = v;
    __syncthreads();
    if (tid == 0) {
        float tot = part[0] + part[1] + part[2] + part[3];
        atomicAdd(out, tot * (1.0f / (BATCH * NPTS)));
    }
}

// ================= fallback: proven 3-kernel brute force (r5/r8) =================
__global__ void chamfer_init(unsigned int* mins, float* out) {
    int i = blockIdx.x * blockDim.x + threadIdx.x;
    mins[i] = 0x7F800000u;
    if (i == 0) out[0] = 0.0f;
}

#define FB_QPT 16
#define FB_SLICES 64
#define FB_SLICE (NPTS / FB_SLICES)

__global__ __launch_bounds__(THREADS, 4) void chamfer_brute(
    const float* __restrict__ p1, const float* __restrict__ p2,
    unsigned int* __restrict__ mins)
{
    const int tid  = threadIdx.x;
    const int bz   = blockIdx.z;
    const int dir  = bz >> 2;
    const int b    = bz & 3;
    const int qbase = blockIdx.x * (THREADS * FB_QPT);
    const int tbase = blockIdx.y * FB_SLICE;
    const float* __restrict__ qsrc = (dir == 0) ? p1 : p2;
    const float* __restrict__ tsrc = (dir == 0) ? p2 : p1;

    __shared__ f4 tgt[FB_SLICE];
    {
        const float* tp = tsrc + ((size_t)b * NPTS + tbase) * 3;
        for (int k = tid; k < FB_SLICE; k += THREADS) {
            float x = tp[k * 3 + 0], y = tp[k * 3 + 1], z = tp[k * 3 + 2];
            tgt[k] = f4{-2.0f * x, -2.0f * y, -2.0f * z,
                        fmaf(x, x, fmaf(y, y, z * z))};
        }
    }
    float qx[FB_QPT], qy[FB_QPT], qz[FB_QPT], best[FB_QPT];
#pragma unroll
    for (int j = 0; j < FB_QPT; ++j) {
        const int q = qbase + j * THREADS + tid;
        const float* pq = qsrc + ((size_t)b * NPTS + q) * 3;
        qx[j] = pq[0]; qy[j] = pq[1]; qz[j] = pq[2];
        best[j] = 3.0e38f;
    }
    __syncthreads();
#pragma unroll 2
    for (int m = 0; m < FB_SLICE; m += 2) {
        f4 ta = tgt[m], tb = tgt[m + 1];
#pragma unroll
        for (int j = 0; j < FB_QPT; ++j) {
            float da = fmaf(qz[j], ta.z, ta.w);
            da = fmaf(qy[j], ta.y, da);
            da = fmaf(qx[j], ta.x, da);
            float db = fmaf(qz[j], tb.z, tb.w);
            db = fmaf(qy[j], tb.y, db);
            db = fmaf(qx[j], tb.x, db);
            best[j] = fminf(fminf(best[j], da), db);
        }
    }
    unsigned int* mbase = mins + ((size_t)dir * BATCH + b) * NPTS;
#pragma unroll
    for (int j = 0; j < FB_QPT; ++j) {
        float q2 = fmaf(qx[j], qx[j], fmaf(qy[j], qy[j], qz[j] * qz[j]));
        float v = fmaxf(best[j] + q2, 0.0f);
        atomicMin(&mbase[qbase + j * THREADS + tid], __float_as_uint(v));
    }
}

__global__ __launch_bounds__(THREADS) void chamfer_reduce(
    const uint4* __restrict__ mins, float* __restrict__ out)
{
    const int i = blockIdx.x * THREADS + threadIdx.x;
    uint4 u = mins[i];
    float s = __uint_as_float(u.x) + __uint_as_float(u.y)
            + __uint_as_float(u.z) + __uint_as_float(u.w);
#pragma unroll
    for (int off = 32; off >= 1; off >>= 1)
        s += __shfl_down(s, off, 64);
    __shared__ float partial[THREADS / 64];
    if ((threadIdx.x & 63) == 0) partial[threadIdx.x >> 6] = s;
    __syncthreads();
    if (threadIdx.x == 0) {
        float tot = 0.0f;
#pragma unroll
        for (int w = 0; w < THREADS / 64; ++w) tot += partial[w];
        atomicAdd(out, tot * (1.0f / (BATCH * NPTS)));
    }
}

extern "C" void kernel_launch(void* const* d_in, const int* in_sizes, int n_in,
                              void* d_out, int out_size, void* d_ws, size_t ws_size,
                              hipStream_t stream) {
    const float* p1 = (const float*)d_in[0];
    const float* p2 = (const float*)d_in[1];
    float* out = (float*)d_out;

    if (ws_size >= (size_t)WS_NEEDED) {
        f4* sortedT = (f4*)d_ws;
        unsigned int* binStart = (unsigned int*)((char*)d_ws + OFF_BINSTART);
        float* meta = (float*)((char*)d_ws + OFF_META);

        chamfer_prep<<<NSETS, 1024, 0, stream>>>(p1, p2, sortedT, binStart, meta, out);
        chamfer_query<<<NMINS / THREADS, THREADS, 0, stream>>>(
            p1, p2, sortedT, binStart, meta, out);
    } else {
        unsigned int* mins = (unsigned int*)d_ws;
        chamfer_init<<<NMINS / THREADS, THREADS, 0, stream>>>(mins, out);
        dim3 grid(NPTS / (THREADS * FB_QPT), FB_SLICES, 2 * BATCH);
        chamfer_brute<<<grid, THREADS, 0, stream>>>(p1, p2, mins);
        chamfer_reduce<<<NMINS / (4 * THREADS), THREADS, 0, stream>>>(
            (const uint4*)mins, out);
    }
}

// Round 10
// 201.720 us; speedup vs baseline: 2.5718x; 2.5718x over previous
//
#include <hip/hip_runtime.h>

#define THREADS 256
#define QPT 16                  // p1 rows per thread (register side)
#define NPTS 8192
#define BATCH 4
#define SLICE 64                // p2 targets per block (LDS side)
#define SLICES (NPTS / SLICE)   // 128
#define XTILES (NPTS / (THREADS * QPT))   // 2
#define NROWS (BATCH * NPTS)    // 32768

typedef float f4 __attribute__((ext_vector_type(4)));

// ---------------- ws layout (symmetric path) ----------------
// rowpart[b][y][8192] : BATCH*SLICES*NPTS floats = 16 MB  (min over slice y's targets)
// colpart[b][x][8192] : BATCH*XTILES*NPTS floats = 256 KB (min over row-tile x's rows)
#define ROWPART_FLOATS ((size_t)BATCH * SLICES * NPTS)
#define COLPART_FLOATS ((size_t)BATCH * XTILES * NPTS)
#define WS_NEEDED ((ROWPART_FLOATS + COLPART_FLOATS) * 4)

// ================= symmetric main: each unique pair once =================
// dist[n,m] = |q_n|^2 + |t_m|^2 - 2 q.t ; row fold tracks partial (no q^2,
// constant per row); col fold needs full value (+q2[j] add).
__global__ __launch_bounds__(THREADS, 4) void chamfer_sym(
    const float* __restrict__ p1, const float* __restrict__ p2,
    float* __restrict__ rowpart, float* __restrict__ colpart,
    float* __restrict__ out)
{
    const int tid = threadIdx.x;
    const int bx  = blockIdx.x;          // 0..XTILES-1 : row tile
    const int by  = blockIdx.y;          // 0..SLICES-1 : target slice
    const int b   = blockIdx.z;          // batch
    const int qbase = bx * (THREADS * QPT);
    const int tbase = by * SLICE;

    // ---- stage p2 slice into LDS: (-2x,-2y,-2z,|t|^2), + col-min array ----
    __shared__ f4 tgt[SLICE];
    __shared__ unsigned int cmin[SLICE];
    if (tid < SLICE) {
        const float* tp = p2 + ((size_t)b * NPTS + tbase + tid) * 3;
        float x = tp[0], y = tp[1], z = tp[2];
        tgt[tid] = f4{-2.0f * x, -2.0f * y, -2.0f * z,
                      fmaf(x, x, fmaf(y, y, z * z))};
        cmin[tid] = 0x7F800000u;         // +inf
    }

    // ---- p1 rows in registers ----
    float qx[QPT], qy[QPT], qz[QPT], q2[QPT], best[QPT];
#pragma unroll
    for (int j = 0; j < QPT; ++j) {
        const int q = qbase + j * THREADS + tid;
        const float* pq = p1 + ((size_t)b * NPTS + q) * 3;
        qx[j] = pq[0]; qy[j] = pq[1]; qz[j] = pq[2];
        q2[j] = fmaf(qx[j], qx[j], fmaf(qy[j], qy[j], qz[j] * qz[j]));
        best[j] = 3.0e38f;
    }
    __syncthreads();

    // ---- main loop: 2 targets/iter; row fold in regs, col fold via
    // per-thread running min -> 64-lane shfl reduce -> LDS atomicMin ----
#pragma unroll 2
    for (int m = 0; m < SLICE; m += 2) {
        f4 ta = tgt[m];
        f4 tb = tgt[m + 1];
        float ca = 3.0e38f, cb = 3.0e38f;
#pragma unroll
        for (int j = 0; j < QPT; ++j) {
            float da = fmaf(qz[j], ta.z, ta.w);
            da = fmaf(qy[j], ta.y, da);
            da = fmaf(qx[j], ta.x, da);
            float db = fmaf(qz[j], tb.z, tb.w);
            db = fmaf(qy[j], tb.y, db);
            db = fmaf(qx[j], tb.x, db);
            best[j] = fminf(fminf(best[j], da), db);   // row fold (partial)
            ca = fminf(ca, da + q2[j]);                // col fold (full)
            cb = fminf(cb, db + q2[j]);
        }
        // 64-lane min reduce (DS-pipe shuffles, cheap vs VALU)
#pragma unroll
        for (int off = 1; off < 64; off <<= 1) {
            ca = fminf(ca, __shfl_xor(ca, off, 64));
            cb = fminf(cb, __shfl_xor(cb, off, 64));
        }
        if ((tid & 63) == 0) {
            atomicMin(&cmin[m],     __float_as_uint(fmaxf(ca, 0.0f)));
            atomicMin(&cmin[m + 1], __float_as_uint(fmaxf(cb, 0.0f)));
        }
    }
    __syncthreads();

    // ---- race-free partial stores (disjoint per block) ----
    float* rp = rowpart + ((size_t)(b * SLICES + by)) * NPTS;
#pragma unroll
    for (int j = 0; j < QPT; ++j) {
        float v = fmaxf(best[j] + q2[j], 0.0f);
        rp[qbase + j * THREADS + tid] = v;
    }
    if (tid < SLICE)
        colpart[((size_t)(b * XTILES + bx)) * NPTS + tbase + tid] =
            __uint_as_float(cmin[tid]);

    if (bx == 0 && by == 0 && b == 0 && tid == 0)
        out[0] = 0.0f;                   // reduce runs in a later dispatch
}

// ================= finish: min over partials, sum, scale =================
__global__ __launch_bounds__(THREADS) void chamfer_finish(
    const float* __restrict__ rowpart, const float* __restrict__ colpart,
    float* __restrict__ out)
{
    const int tid = threadIdx.x;
    const int gid = blockIdx.x * THREADS + tid;   // 0..32767
    const int b   = gid >> 13;
    const int r   = gid & (NPTS - 1);

    float m = 3.0e38f;
    const float* rb = rowpart + (size_t)b * SLICES * NPTS + r;
#pragma unroll 8
    for (int y = 0; y < SLICES; ++y)
        m = fminf(m, rb[(size_t)y * NPTS]);

    const float* cb = colpart + (size_t)b * XTILES * NPTS + r;
    float c = fminf(cb[0], cb[(size_t)NPTS]);

    float s = m + c;
#pragma unroll
    for (int off = 1; off < 64; off <<= 1)
        s += __shfl_xor(s, off, 64);
    __shared__ float part[THREADS / 64];
    if ((tid & 63) == 0) part[tid >> 6] = s;
    __syncthreads();
    if (tid == 0) {
        float tot = part[0] + part[1] + part[2] + part[3];
        atomicAdd(out, tot * (1.0f / (BATCH * NPTS)));
    }
}

// ================= fallback: proven 3-kernel brute force (r8) =================
#define NMINS (2 * BATCH * NPTS)
#define FB_QPT 16
#define FB_SLICES 64
#define FB_SLICE (NPTS / FB_SLICES)

__global__ void chamfer_init(unsigned int* mins, float* out) {
    int i = blockIdx.x * blockDim.x + threadIdx.x;
    mins[i] = 0x7F800000u;
    if (i == 0) out[0] = 0.0f;
}

__global__ __launch_bounds__(THREADS, 4) void chamfer_brute(
    const float* __restrict__ p1, const float* __restrict__ p2,
    unsigned int* __restrict__ mins)
{
    const int tid  = threadIdx.x;
    const int bz   = blockIdx.z;
    const int dir  = bz >> 2;
    const int b    = bz & 3;
    const int qbase = blockIdx.x * (THREADS * FB_QPT);
    const int tbase = blockIdx.y * FB_SLICE;
    const float* __restrict__ qsrc = (dir == 0) ? p1 : p2;
    const float* __restrict__ tsrc = (dir == 0) ? p2 : p1;

    __shared__ f4 tgt[FB_SLICE];
    {
        const float* tp = tsrc + ((size_t)b * NPTS + tbase) * 3;
        for (int k = tid; k < FB_SLICE; k += THREADS) {
            float x = tp[k * 3 + 0], y = tp[k * 3 + 1], z = tp[k * 3 + 2];
            tgt[k] = f4{-2.0f * x, -2.0f * y, -2.0f * z,
                        fmaf(x, x, fmaf(y, y, z * z))};
        }
    }
    float qx[FB_QPT], qy[FB_QPT], qz[FB_QPT], best[FB_QPT];
#pragma unroll
    for (int j = 0; j < FB_QPT; ++j) {
        const int q = qbase + j * THREADS + tid;
        const float* pq = qsrc + ((size_t)b * NPTS + q) * 3;
        qx[j] = pq[0]; qy[j] = pq[1]; qz[j] = pq[2];
        best[j] = 3.0e38f;
    }
    __syncthreads();
#pragma unroll 2
    for (int m = 0; m < FB_SLICE; m += 2) {
        f4 ta = tgt[m], tb = tgt[m + 1];
#pragma unroll
        for (int j = 0; j < FB_QPT; ++j) {
            float da = fmaf(qz[j], ta.z, ta.w);
            da = fmaf(qy[j], ta.y, da);
            da = fmaf(qx[j], ta.x, da);
            float db = fmaf(qz[j], tb.z, tb.w);
            db = fmaf(qy[j], tb.y, db);
            db = fmaf(qx[j], tb.x, db);
            best[j] = fminf(fminf(best[j], da), db);
        }
    }
    unsigned int* mbase = mins + ((size_t)dir * BATCH + b) * NPTS;
#pragma unroll
    for (int j = 0; j < FB_QPT; ++j) {
        float q2 = fmaf(qx[j], qx[j], fmaf(qy[j], qy[j], qz[j] * qz[j]));
        float v = fmaxf(best[j] + q2, 0.0f);
        atomicMin(&mbase[qbase + j * THREADS + tid], __float_as_uint(v));
    }
}

__global__ __launch_bounds__(THREADS) void chamfer_reduce(
    const uint4* __restrict__ mins, float* __restrict__ out)
{
    const int i = blockIdx.x * THREADS + threadIdx.x;
    uint4 u = mins[i];
    float s = __uint_as_float(u.x) + __uint_as_float(u.y)
            + __uint_as_float(u.z) + __uint_as_float(u.w);
#pragma unroll
    for (int off = 32; off >= 1; off >>= 1)
        s += __shfl_down(s, off, 64);
    __shared__ float partial[THREADS / 64];
    if ((threadIdx.x & 63) == 0) partial[threadIdx.x >> 6] = s;
    __syncthreads();
    if (threadIdx.x == 0) {
        float tot = 0.0f;
#pragma unroll
        for (int w = 0; w < THREADS / 64; ++w) tot += partial[w];
        atomicAdd(out, tot * (1.0f / (BATCH * NPTS)));
    }
}

extern "C" void kernel_launch(void* const* d_in, const int* in_sizes, int n_in,
                              void* d_out, int out_size, void* d_ws, size_t ws_size,
                              hipStream_t stream) {
    const float* p1 = (const float*)d_in[0];
    const float* p2 = (const float*)d_in[1];
    float* out = (float*)d_out;

    if (ws_size >= WS_NEEDED) {
        float* rowpart = (float*)d_ws;
        float* colpart = rowpart + ROWPART_FLOATS;

        // main: x = row tiles (2), y = target slices (128), z = batch (4) -> 1024 blocks
        dim3 grid(XTILES, SLICES, BATCH);
        chamfer_sym<<<grid, THREADS, 0, stream>>>(p1, p2, rowpart, colpart, out);

        // finish: 32768 rows+cols / 256 = 128 blocks
        chamfer_finish<<<NROWS / THREADS, THREADS, 0, stream>>>(rowpart, colpart, out);
    } else {
        unsigned int* mins = (unsigned int*)d_ws;
        chamfer_init<<<NMINS / THREADS, THREADS, 0, stream>>>(mins, out);
        dim3 grid(NPTS / (THREADS * FB_QPT), FB_SLICES, 2 * BATCH);
        chamfer_brute<<<grid, THREADS, 0, stream>>>(p1, p2, mins);
        chamfer_reduce<<<NMINS / (4 * THREADS), THREADS, 0, stream>>>(
            (const uint4*)mins, out);
    }
}

// Round 11
// 96.005 us; speedup vs baseline: 5.4038x; 2.1011x over previous
//
#include <hip/hip_runtime.h>

#define THREADS 256
#define QPT 8              // queries per thread, scalar registers
#define SLICES 128
#define NPTS 8192
#define BATCH 4
#define SLICE (NPTS / SLICES)   // 64 targets per block
#define NMINS (2 * BATCH * NPTS)            // 65536

typedef float f4 __attribute__((ext_vector_type(4)));

// ws layout: [2][BATCH][NPTS] uint (float bits) min arrays = 65536 entries = 256 KB

__global__ void chamfer_init(unsigned int* mins, float* out) {
    int i = blockIdx.x * blockDim.x + threadIdx.x;
    mins[i] = 0x7F800000u;  // +inf
    if (i == 0) out[0] = 0.0f;
}

// __launch_bounds__(256, 8): 8 waves/EU min => 8 blocks/CU resident, VGPR cap 64.
// QPT=8 needs ~44 VGPR (r5 measured) -- fits without spill.
__global__ __launch_bounds__(THREADS, 8) void chamfer_main(
    const float* __restrict__ p1, const float* __restrict__ p2,
    unsigned int* __restrict__ mins)
{
    const int tid  = threadIdx.x;
    const int bz   = blockIdx.z;         // 0..7 : dir*4 + batch
    const int dir  = bz >> 2;
    const int b    = bz & 3;
    const int qbase = blockIdx.x * (THREADS * QPT);
    const int tbase = blockIdx.y * SLICE;

    const float* __restrict__ qsrc = (dir == 0) ? p1 : p2;
    const float* __restrict__ tsrc = (dir == 0) ? p2 : p1;

    // ---- stage transformed targets into LDS: (-2x, -2y, -2z, |t|^2) ----
    __shared__ f4 tgt[SLICE];
    if (tid < SLICE) {
        const float* tp = tsrc + ((size_t)b * NPTS + tbase + tid) * 3;
        float x = tp[0], y = tp[1], z = tp[2];
        tgt[tid] = f4{-2.0f * x, -2.0f * y, -2.0f * z,
                      fmaf(x, x, fmaf(y, y, z * z))};
    }

    // ---- load this thread's queries into scalar registers ----
    float qx[QPT], qy[QPT], qz[QPT], best[QPT];
#pragma unroll
    for (int j = 0; j < QPT; ++j) {
        const int q = qbase + j * THREADS + tid;
        const float* pq = qsrc + ((size_t)b * NPTS + q) * 3;
        qx[j] = pq[0];
        qy[j] = pq[1];
        qz[j] = pq[2];
        best[j] = 3.0e38f;
    }

    __syncthreads();

    // ---- main loop: 2 targets/iter, scalar FMA chains + min3 fold ----
#pragma unroll 2
    for (int m = 0; m < SLICE; m += 2) {
        f4 ta = tgt[m];
        f4 tb = tgt[m + 1];
#pragma unroll
        for (int j = 0; j < QPT; ++j) {
            float da = fmaf(qz[j], ta.z, ta.w);
            da = fmaf(qy[j], ta.y, da);
            da = fmaf(qx[j], ta.x, da);
            float db = fmaf(qz[j], tb.z, tb.w);
            db = fmaf(qy[j], tb.y, db);
            db = fmaf(qx[j], tb.x, db);
            best[j] = fminf(fminf(best[j], da), db);   // -> v_min3_f32
        }
    }

    // ---- epilogue: + |q|^2, clamp tiny negative from cancellation ----
    unsigned int* mbase = mins + ((size_t)dir * BATCH + b) * NPTS;
#pragma unroll
    for (int j = 0; j < QPT; ++j) {
        float q2 = fmaf(qx[j], qx[j], fmaf(qy[j], qy[j], qz[j] * qz[j]));
        float v = fmaxf(best[j] + q2, 0.0f);
        atomicMin(&mbase[qbase + j * THREADS + tid], __float_as_uint(v));
    }
}

__global__ __launch_bounds__(THREADS) void chamfer_reduce(
    const uint4* __restrict__ mins, float* __restrict__ out)
{
    const int i = blockIdx.x * THREADS + threadIdx.x;   // 64 blocks * 256 = 16384 uint4
    uint4 u = mins[i];
    float s = __uint_as_float(u.x) + __uint_as_float(u.y)
            + __uint_as_float(u.z) + __uint_as_float(u.w);
#pragma unroll
    for (int off = 32; off >= 1; off >>= 1)
        s += __shfl_down(s, off, 64);
    __shared__ float partial[THREADS / 64];
    if ((threadIdx.x & 63) == 0) partial[threadIdx.x >> 6] = s;
    __syncthreads();
    if (threadIdx.x == 0) {
        float tot = 0.0f;
#pragma unroll
        for (int w = 0; w < THREADS / 64; ++w) tot += partial[w];
        atomicAdd(out, tot * (1.0f / (BATCH * NPTS)));
    }
}

extern "C" void kernel_launch(void* const* d_in, const int* in_sizes, int n_in,
                              void* d_out, int out_size, void* d_ws, size_t ws_size,
                              hipStream_t stream) {
    const float* p1 = (const float*)d_in[0];
    const float* p2 = (const float*)d_in[1];
    unsigned int* mins = (unsigned int*)d_ws;   // 65536 uints
    float* out = (float*)d_out;

    // init mins to +inf, out to 0
    chamfer_init<<<NMINS / THREADS, THREADS, 0, stream>>>(mins, out);

    // main: x = query blocks (8192/(256*8)=4), y = target slices (128), z = dir*4+batch
    dim3 grid(NPTS / (THREADS * QPT), SLICES, 2 * BATCH);
    chamfer_main<<<grid, THREADS, 0, stream>>>(p1, p2, mins);

    // parallel reduce: 65536 mins / 4 per thread / 256 per block = 64 blocks
    chamfer_reduce<<<NMINS / (4 * THREADS), THREADS, 0, stream>>>(
        (const uint4*)mins, out);
}